// Round 13
// baseline (713.208 us; speedup 1.0000x reference)
//
#include <hip/hip_runtime.h>
#include <stdint.h>

typedef signed char i8;
typedef int v4i __attribute__((ext_vector_type(4)));

#define S_IN  0.05f
#define S_Z   0.02f
#define S_U   0.01f
#define S_DTLN 0.02f
#define S_B   0.02f
#define S_C   0.02f
#define S_DT  0.01f
#define S_Y   0.01f

// qa(): round-half-even (matches jnp.round), clip to [-128,127]
__device__ __forceinline__ float q8f(float x, float s) {
    float r = rintf(x / s);
    return fmaxf(-128.0f, fminf(127.0f, r));
}
__device__ __forceinline__ int q8i(float x, float s) { return (int)q8f(x, s); }

__device__ __forceinline__ float softplus_f(float x) {
    return __fadd_rn(fmaxf(x, 0.0f), log1pf(expf(-fabsf(x))));
}

__device__ __forceinline__ int sbyte_of(int w, int j) {
    return (int)(signed char)((unsigned)w >> (j * 8));
}
__device__ __forceinline__ int ubyte_of(int w, int j) {
    return (int)(((unsigned)w >> (j * 8)) & 255u);
}

// async global->LDS, 16B per lane; LDS dest = wave-uniform base + lane*16
__device__ __forceinline__ void gload16(const i8* g, i8* lds) {
    __builtin_amdgcn_global_load_lds(
        (const __attribute__((address_space(1))) unsigned int*)g,
        (__attribute__((address_space(3))) unsigned int*)lds,
        16, 0, 0);
}

// ---------------- fused max|w| over the 5 weight tensors ----------------
__global__ __launch_bounds__(256)
void k_maxabs_all(const float* __restrict__ a0, const float* __restrict__ a1,
                  const float* __restrict__ a2, const float* __restrict__ a3,
                  const float* __restrict__ a4, unsigned* __restrict__ out) {
    int bid = blockIdx.x;
    const float* w; long long n; int slot, nb;
    if (bid < 2048)      { w = a0; n = 16777216LL; slot = 0; nb = 2048; }
    else if (bid < 2112) { w = a1; n = 16384LL;    slot = 1; nb = 64;   bid -= 2048; }
    else if (bid < 2624) { w = a2; n = 655360LL;   slot = 2; nb = 512;  bid -= 2112; }
    else if (bid < 3136) { w = a3; n = 524288LL;   slot = 3; nb = 512;  bid -= 2624; }
    else                 { w = a4; n = 8388608LL;  slot = 4; nb = 1024; bid -= 3136; }
    unsigned m = 0;
    long long stride = (long long)nb * 256;
    for (long long i = (long long)bid * 256 + threadIdx.x; i < n; i += stride)
        m = max(m, __float_as_uint(fabsf(w[i])));
    #pragma unroll
    for (int off = 32; off; off >>= 1) {
        unsigned o = (unsigned)__shfl_xor((int)m, off);
        m = max(m, o);
    }
    __shared__ unsigned sm[4];
    if ((threadIdx.x & 63) == 0) sm[threadIdx.x >> 6] = m;
    __syncthreads();
    if (threadIdx.x == 0) {
        unsigned r = max(max(sm[0], sm[1]), max(sm[2], sm[3]));
        atomicMax(out + slot, r);
    }
}

// ---------------- fused quant: 4 weights + hidden activation ----------------
__global__ __launch_bounds__(256)
void k_quant_all(const float* __restrict__ a0, const float* __restrict__ a1,
                 const float* __restrict__ a2, const float* __restrict__ a3,
                 const float* __restrict__ ax, const unsigned* __restrict__ scales,
                 i8* __restrict__ o0, i8* __restrict__ o1, i8* __restrict__ o2,
                 i8* __restrict__ o3, i8* __restrict__ ox) {
    int bid = blockIdx.x;
    const float* w; i8* o; float s;
    if (bid < 16384)      { w = a0; o = o0; s = __uint_as_float(scales[0]) / 127.0f; }
    else if (bid < 16400) { w = a1; o = o1; s = __uint_as_float(scales[1]) / 127.0f; bid -= 16384; }
    else if (bid < 17040) { w = a2; o = o2; s = __uint_as_float(scales[2]) / 127.0f; bid -= 16400; }
    else if (bid < 17552) { w = a3; o = o3; s = __uint_as_float(scales[3]) / 127.0f; bid -= 17040; }
    else                  { w = ax; o = ox; s = S_IN;                                 bid -= 17552; }
    long long i = ((long long)bid * 256 + threadIdx.x) * 4;
    float4 v = *(const float4*)(w + i);
    unsigned pk = ((unsigned)(q8i(v.x, s) & 255))
                | ((unsigned)(q8i(v.y, s) & 255) << 8)
                | ((unsigned)(q8i(v.z, s) & 255) << 16)
                | ((unsigned)(q8i(v.w, s) & 255) << 24);
    *(unsigned*)(o + i) = pk;
}

// ---------------- single weight quant (out_proj, runs after GEMM1) ----------------
__global__ __launch_bounds__(256)
void k_quant_w(const float* __restrict__ w, long long n,
               const unsigned* __restrict__ maxbits, i8* __restrict__ o) {
    long long i = ((long long)blockIdx.x * 256 + threadIdx.x) * 4;
    if (i >= n) return;
    float s = __uint_as_float(*maxbits) / 127.0f;
    float4 v = *(const float4*)(w + i);
    unsigned pk = ((unsigned)(q8i(v.x, s) & 255))
                | ((unsigned)(q8i(v.y, s) & 255) << 8)
                | ((unsigned)(q8i(v.z, s) & 255) << 16)
                | ((unsigned)(q8i(v.w, s) & 255) << 24);
    *(unsigned*)(o + i) = pk;
}

// ---------------- MFMA int8 GEMM: LDS-staged, 128x128 tile, BK=128 bytes ----------------
template<int EPI>
__global__ __launch_bounds__(256)
void k_mgemm(const i8* __restrict__ A, const i8* __restrict__ Bw,
             int M, int N, int K,
             const unsigned* __restrict__ wmaxbits,
             void* __restrict__ out0, void* __restrict__ out1) {
    __shared__ i8 sA[16384];
    __shared__ i8 sB[16384];
    const int tid = threadIdx.x;
    const int w = tid >> 6;
    const int l = tid & 63;
    int id = blockIdx.y * gridDim.x + blockIdx.x;
    const int qq = (gridDim.x * gridDim.y) >> 3;
    id = (id & 7) * qq + (id >> 3);
    const int m0 = (id / gridDim.x) << 7;
    const int n0 = (id % gridDim.x) << 7;
    const int kLen = K / gridDim.z;
    const int kOff = blockIdx.z * kLen;
    const int lr = l & 15;
    const int lk = l >> 4;
    const i8* gA = A  + (size_t)(m0 + lr) * K + lk * 16;
    const i8* gB = Bw + (size_t)(n0 + lr) * K + lk * 16;
    const size_t rowK16 = (size_t)16 * K;
    const int mw = (w >> 1) * 4;
    const int nw = (w & 1) * 4;
    const int rdoff = lk * 256 + lr * 16;
    v4i acc[4][4] = {};
    for (int k0 = kOff; k0 < kOff + kLen; k0 += 128) {
        gload16(gA + rowK16 * w + k0,            sA + w * 2048);
        gload16(gA + rowK16 * w + k0 + 64,       sA + w * 2048 + 1024);
        gload16(gA + rowK16 * (4 + w) + k0,      sA + (4 + w) * 2048);
        gload16(gA + rowK16 * (4 + w) + k0 + 64, sA + (4 + w) * 2048 + 1024);
        gload16(gB + rowK16 * w + k0,            sB + w * 2048);
        gload16(gB + rowK16 * w + k0 + 64,       sB + w * 2048 + 1024);
        gload16(gB + rowK16 * (4 + w) + k0,      sB + (4 + w) * 2048);
        gload16(gB + rowK16 * (4 + w) + k0 + 64, sB + (4 + w) * 2048 + 1024);
        __syncthreads();
        #pragma unroll
        for (int k64 = 0; k64 < 2; k64++) {
            v4i af[4], bf[4];
            #pragma unroll
            for (int t = 0; t < 4; t++) {
                af[t] = *(const v4i*)(sA + (mw + t) * 2048 + k64 * 1024 + rdoff);
                bf[t] = *(const v4i*)(sB + (nw + t) * 2048 + k64 * 1024 + rdoff);
            }
            #pragma unroll
            for (int mt = 0; mt < 4; mt++)
                #pragma unroll
                for (int nt = 0; nt < 4; nt++)
                    acc[mt][nt] = __builtin_amdgcn_mfma_i32_16x16x64_i8(af[mt], bf[nt], acc[mt][nt], 0, 0, 0);
        }
        __syncthreads();
    }
    const float wsc = __uint_as_float(*wmaxbits) / 127.0f;
    const int m0w = m0 + (w >> 1) * 64;
    const int n0w = n0 + (w & 1) * 64;
    if constexpr (EPI == 0 || EPI == 2) {
        const float sc = (EPI == 0 ? S_IN : S_DTLN) * wsc;
        const float qs = (EPI == 0 ? S_Z : S_DT);
        const int b = m0w >> 11;
        #pragma unroll
        for (int nt = 0; nt < 4; nt++) {
            const int j = n0w + nt * 16 + lr;
            i8* dst;
            if constexpr (EPI == 0) dst = (j < 4096) ? (i8*)out0 : (i8*)out1;
            else dst = (i8*)out0;
            const int jj = j & 4095;
            #pragma unroll
            for (int mt = 0; mt < 4; mt++) {
                const int sbase = (m0w & 2047) + mt * 16 + lk * 4;
                unsigned pk = 0;
                #pragma unroll
                for (int r = 0; r < 4; r++) {
                    float v = (float)acc[mt][nt][r] * sc;
                    pk |= ((unsigned)(q8i(v, qs) & 255)) << (8 * r);
                }
                *(unsigned*)(dst + ((size_t)b * 4096 + jj) * 2048 + sbase) = pk;
            }
        }
    } else if constexpr (EPI == 1) {
        int* O = (int*)out0;
        #pragma unroll
        for (int mt = 0; mt < 4; mt++)
            #pragma unroll
            for (int r = 0; r < 4; r++) {
                const int m = m0w + mt * 16 + lk * 4 + r;
                #pragma unroll
                for (int nt = 0; nt < 4; nt++) {
                    const int j = n0w + nt * 16 + lr;
                    if (j < 160)
                        atomicAdd(O + (size_t)m * 160 + j, acc[mt][nt][r]);
                }
            }
    } else {
        const float sc = S_Y * wsc;
        float* O = (float*)out0;
        #pragma unroll
        for (int mt = 0; mt < 4; mt++)
            #pragma unroll
            for (int r = 0; r < 4; r++) {
                const int m = m0w + mt * 16 + lk * 4 + r;
                #pragma unroll
                for (int nt = 0; nt < 4; nt++)
                    O[(size_t)m * N + n0w + nt * 16 + lr] = (float)acc[mt][nt][r] * sc;
            }
    }
}

// ---------------- depthwise causal conv(K=4) + silu + quant ----------------
__global__ __launch_bounds__(256)
void k_conv(const i8* __restrict__ hsq, const i8* __restrict__ cwq,
            const float* __restrict__ conv_b, const unsigned* __restrict__ cmaxbits,
            i8* __restrict__ uq, i8* __restrict__ uqT) {
    __shared__ char lt[64][68];
    const int tid = threadIdx.x;
    const int b = blockIdx.z;
    const int d0 = blockIdx.y << 6;
    const int s0 = blockIdx.x << 6;
    const int dl = tid >> 2;
    const int sg = tid & 3;
    const int d = d0 + dl;
    const int sbase = s0 + (sg << 4);
    const i8* xp = hsq + ((size_t)b * 4096 + d) * 2048;
    int v[19];
    #pragma unroll
    for (int i = 0; i < 19; i++) {
        int s = sbase - 3 + i;
        v[i] = (s >= 0) ? (int)xp[s] : 0;
    }
    const unsigned cw = *(const unsigned*)(cwq + (size_t)d * 4);
    const int w0 = (int)(char)(cw & 255);
    const int w1 = (int)(char)((cw >> 8) & 255);
    const int w2 = (int)(char)((cw >> 16) & 255);
    const int w3 = (int)(char)((cw >> 24) & 255);
    const float cws = __uint_as_float(*cmaxbits) / 127.0f;
    const float sc = S_Z * cws;
    const float bias = conv_b[d];
    unsigned pk[4] = {0, 0, 0, 0};
    #pragma unroll
    for (int t = 0; t < 16; t++) {
        int acc = v[t] * w0 + v[t + 1] * w1 + v[t + 2] * w2 + v[t + 3] * w3;
        float f = __fadd_rn(__fmul_rn((float)acc, sc), bias);
        float sig = 1.0f / (1.0f + expf(-f));
        float sl = __fmul_rn(f, sig);
        int q = q8i(sl, S_U);
        pk[t >> 2] |= ((unsigned)(q & 255)) << ((t & 3) * 8);
        lt[(sg << 4) + t][dl] = (char)q;
    }
    *(int4*)(uq + ((size_t)b * 4096 + d) * 2048 + sbase) = make_int4(pk[0], pk[1], pk[2], pk[3]);
    __syncthreads();
    const int rr = tid >> 2;
    const int wg = tid & 3;
    const int* rp = (const int*)(&lt[rr][wg << 4]);
    int4 o; o.x = rp[0]; o.y = rp[1]; o.z = rp[2]; o.w = rp[3];
    *(int4*)(uqT + ((size_t)b * 2048 + s0 + rr) * 4096 + d0 + (wg << 4)) = o;
}

// ---------------- rmsnorm + quant; input int32 partials; B/C transposed ----------------
__global__ __launch_bounds__(64)
void k_rms(const int* __restrict__ p, const unsigned* __restrict__ xsc,
           const float* __restrict__ wdt, const float* __restrict__ wB, const float* __restrict__ wC,
           i8* __restrict__ dtq, i8* __restrict__ bqT, i8* __restrict__ cqT) {
    const int row = blockIdx.x;
    const int lane = threadIdx.x;
    const float scp = S_U * (__uint_as_float(*xsc) / 127.0f);
    const int* x = p + (size_t)row * 160;
    float a0 = (float)x[lane] * scp;
    float a1 = (float)x[64 + lane] * scp;
    float bb = (lane < 16) ? (float)x[128 + lane] * scp : 0.0f;
    float cc = (lane < 16) ? (float)x[144 + lane] * scp : 0.0f;
    float sdt = __fadd_rn(__fmul_rn(a0, a0), __fmul_rn(a1, a1));
    float sB = __fmul_rn(bb, bb);
    float sC = __fmul_rn(cc, cc);
    #pragma unroll
    for (int off = 32; off; off >>= 1) {
        sdt = __fadd_rn(sdt, __shfl_xor(sdt, off));
        sB  = __fadd_rn(sB,  __shfl_xor(sB, off));
        sC  = __fadd_rn(sC,  __shfl_xor(sC, off));
    }
    float rdt = 1.0f / sqrtf(sdt / 128.0f + 1e-6f);
    float rB  = 1.0f / sqrtf(sB / 16.0f + 1e-6f);
    float rC  = 1.0f / sqrtf(sC / 16.0f + 1e-6f);
    dtq[(size_t)row * 128 + lane]      = (i8)q8i(__fmul_rn(wdt[lane],      __fmul_rn(a0, rdt)), S_DTLN);
    dtq[(size_t)row * 128 + 64 + lane] = (i8)q8i(__fmul_rn(wdt[64 + lane], __fmul_rn(a1, rdt)), S_DTLN);
    if (lane < 16) {
        size_t tpos = ((size_t)(row >> 11) * 16 + lane) * 2048 + (row & 2047);
        bqT[tpos] = (i8)q8i(__fmul_rn(wB[lane], __fmul_rn(bb, rB)), S_B);
        cqT[tpos] = (i8)q8i(__fmul_rn(wC[lane], __fmul_rn(cc, rC)), S_C);
    }
}

// ---------------- fused LUT builder: blocks 0..4095 dt rows, block 4096 silu ----------------
__global__ __launch_bounds__(256)
void k_lut_all(const float* __restrict__ dt_bias, float* __restrict__ lutdt,
               float* __restrict__ lutsi) {
    const int q = threadIdx.x;
    const int sv = (q < 128) ? q : q - 256;
    if (blockIdx.x < 4096) {
        const int d = blockIdx.x;
        const float bias = dt_bias[d];
        lutdt[(size_t)d * 256 + q] =
            softplus_f(__fadd_rn(__fmul_rn((float)sv, S_DT), bias));
    } else {
        float gv = __fmul_rn((float)sv, S_Z);
        float sg = __fmul_rn(gv, 1.0f / (1.0f + expf(-gv)));
        lutsi[q] = sg;
    }
}

// ---------------- dA LUT builder: lut[d][q][n] = expf(dtv(d,q) * Acoef(d,n)) ----------------
__global__ __launch_bounds__(256)
void k_lut_dA(const float* __restrict__ A_log, const float* __restrict__ dt_bias,
              float* __restrict__ lut) {
    const int d = blockIdx.x;
    const int q = threadIdx.x;
    const int sv = (q < 128) ? q : q - 256;
    const float dtv = softplus_f(__fadd_rn(__fmul_rn((float)sv, S_DT), dt_bias[d]));
    float* row = lut + (size_t)d * 4096 + q * 16;
    #pragma unroll
    for (int n = 0; n < 16; n++) {
        float Acoef = -expf(A_log[(size_t)d * 16 + n]);
        row[n] = expf(__fmul_rn(dtv, Acoef));
    }
}

// ---------------- scan: 16-step tiles + reduce-scatter tree (bit-exact) ----------------
// Group mapping: b INNERMOST (grp = g>>4; b = grp&1; d = grp>>1) so the two b-copies
// of each d share a wave -> dA-LUT row reuse in L1/L2. Pure relabeling, bit-exact.
template<int BIGLUT>
__global__ __launch_bounds__(256)
void k_scan5(const i8* __restrict__ dt8, const i8* __restrict__ uq, const i8* __restrict__ gq,
             const i8* __restrict__ BqT, const i8* __restrict__ CqT,
             const float* __restrict__ lut_dt, const float* __restrict__ lut_silu,
             const float* __restrict__ lut_dA,
             const float* __restrict__ A_log, const float* __restrict__ D_skip,
             i8* __restrict__ yq) {
    const int g = blockIdx.x * 256 + threadIdx.x;
    const int n = g & 15;
    const int grp = g >> 4;
    const int b = grp & 1;
    const int d = grp >> 1;
    const size_t bd = (size_t)b * 4096 + d;
    float Acoef = 0.0f;
    if constexpr (BIGLUT == 0) Acoef = -expf(A_log[(size_t)d * 16 + n]);
    const float Dd = D_skip[d];
    const float* ldt = lut_dt + (size_t)d * 256;
    const float* ldA = lut_dA + (size_t)d * 4096 + n;   // entry stride 16 per q
    const v4i* dtp = (const v4i*)(dt8 + bd * 2048);
    const v4i* up  = (const v4i*)(uq  + bd * 2048);
    const v4i* gp  = (const v4i*)(gq  + bd * 2048);
    const v4i* Bp  = (const v4i*)(BqT + ((size_t)b * 16 + n) * 2048);
    const v4i* Cp  = (const v4i*)(CqT + ((size_t)b * 16 + n) * 2048);
    i8* yp = yq + (size_t)b * 2048 * 4096 + d;
    float h = 0.0f;
    v4i dtw = dtp[0], uw = up[0], gw = gp[0], bw = Bp[0], cw = Cp[0];
    for (int t = 0; t < 128; t++) {
        v4i ndt, nu, ng, nb, nc;
        if (t < 127) { ndt = dtp[t + 1]; nu = up[t + 1]; ng = gp[t + 1]; nb = Bp[t + 1]; nc = Cp[t + 1]; }
        float dtv[16], dA[16], pj[16], Cv[16], y[16];
        #pragma unroll
        for (int j = 0; j < 16; j++)
            dtv[j] = ldt[ubyte_of(dtw[j >> 2], j & 3)];
        if constexpr (BIGLUT) {
            #pragma unroll
            for (int j = 0; j < 16; j++)
                dA[j] = ldA[ubyte_of(dtw[j >> 2], j & 3) << 4];
        } else {
            #pragma unroll
            for (int j = 0; j < 16; j++)
                dA[j] = expf(__fmul_rn(dtv[j], Acoef));
        }
        #pragma unroll
        for (int j = 0; j < 16; j++) {
            float uv = __fmul_rn((float)sbyte_of(uw[j >> 2], j & 3), S_U);
            float Bv = __fmul_rn((float)sbyte_of(bw[j >> 2], j & 3), S_B);
            Cv[j] = __fmul_rn((float)sbyte_of(cw[j >> 2], j & 3), S_C);
            pj[j] = __fmul_rn(__fmul_rn(dtv[j], uv), Bv);
        }
        #pragma unroll
        for (int j = 0; j < 16; j++) {
            h = __fadd_rn(__fmul_rn(h, dA[j]), pj[j]);
            y[j] = __fmul_rn(h, Cv[j]);
        }
        float w8[8];
        #pragma unroll
        for (int i = 0; i < 8; i++) {
            float a = y[2 * i], bq = y[2 * i + 1];
            float snd = (n & 1) ? a : bq;
            float rcv = __shfl_xor(snd, 1);
            float kept = (n & 1) ? bq : a;
            w8[i] = __fadd_rn(kept, rcv);
        }
        float w4[4];
        #pragma unroll
        for (int i = 0; i < 4; i++) {
            float a = w8[2 * i], bq = w8[2 * i + 1];
            float snd = (n & 2) ? a : bq;
            float rcv = __shfl_xor(snd, 2);
            float kept = (n & 2) ? bq : a;
            w4[i] = __fadd_rn(kept, rcv);
        }
        float w2[2];
        #pragma unroll
        for (int i = 0; i < 2; i++) {
            float a = w4[2 * i], bq = w4[2 * i + 1];
            float snd = (n & 4) ? a : bq;
            float rcv = __shfl_xor(snd, 4);
            float kept = (n & 4) ? bq : a;
            w2[i] = __fadd_rn(kept, rcv);
        }
        float ysave;
        {
            float a = w2[0], bq = w2[1];
            float snd = (n & 8) ? a : bq;
            float rcv = __shfl_xor(snd, 8);
            float kept = (n & 8) ? bq : a;
            ysave = __fadd_rn(kept, rcv);
        }
        int uws = (n & 8) ? ((n & 4) ? uw[3] : uw[2]) : ((n & 4) ? uw[1] : uw[0]);
        int gws = (n & 8) ? ((n & 4) ? gw[3] : gw[2]) : ((n & 4) ? gw[1] : gw[0]);
        float uvn = __fmul_rn((float)(int)(signed char)((unsigned)uws >> ((n & 3) * 8)), S_U);
        int gb = (int)(((unsigned)gws >> ((n & 3) * 8)) & 255u);
        float ys = __fadd_rn(ysave, __fmul_rn(uvn, Dd));
        float sg = lut_silu[gb];
        float vv = __fmul_rn(ys, sg);
        yp[(size_t)(t * 16 + n) * 4096] = (i8)q8i(vv, S_Y);
        if (t < 127) { dtw = ndt; uw = nu; gw = ng; bw = nb; cw = nc; }
    }
}

extern "C" void kernel_launch(void* const* d_in, const int* in_sizes, int n_in,
                              void* d_out, int out_size, void* d_ws, size_t ws_size,
                              hipStream_t stream) {
    const float* hidden   = (const float*)d_in[0];
    const float* in_proj  = (const float*)d_in[1];
    const float* conv_w   = (const float*)d_in[2];
    const float* conv_b   = (const float*)d_in[3];
    const float* x_proj   = (const float*)d_in[4];
    const float* dt_ln    = (const float*)d_in[5];
    const float* B_ln     = (const float*)d_in[6];
    const float* C_ln     = (const float*)d_in[7];
    const float* dt_proj  = (const float*)d_in[8];
    const float* dt_bias  = (const float*)d_in[9];
    const float* A_log    = (const float*)d_in[10];
    const float* D_skip   = (const float*)d_in[11];
    const float* out_proj = (const float*)d_in[12];
    float* out = (float*)d_out;

    // ---- workspace layout: base 46,810,368 B; +64 MB dA-LUT if ws permits ----
    char* ws = (char*)d_ws;
    unsigned* scales = (unsigned*)ws;                       // 256 B
    i8* WQ   = (i8*)(ws + 256);                             // 16,777,216: in_proj q8 -> u_qT -> y_q
    i8* XQ   = (i8*)(ws + 16777472);                        //  8,388,608: x_q -> OWQ
    i8* HSQ  = (i8*)(ws + 25166080);                        // 16,777,216: hs_q -> dt8
    char* S0 = ws + 41943296;
    int*  SSMP = (int*)S0;                                  // 2,621,440: ssm_p int32 [4096][160]
    i8* XWQp = (i8*)(S0 + 2621440);                         // 1,048,576: x_proj q8 padded [256][4096]
    i8* DTQb = (i8*)(S0 + 3670016);                         //   524,288: dt_q [4096][128]
    i8* DWQ  = (i8*)(S0 + 4194304);                         //   524,288: dt_proj q8
    i8* CWQ  = (i8*)(S0 + 4718592);                         //    16,384: conv q8
    float* LUTSI = (float*)(S0 + 4734976);                  //     1,024
    i8* BQT  = (i8*)(S0 + 4736000);                         //    65,536: B_q^T [2][16][2048]
    i8* CQT  = (i8*)(S0 + 4801536);                         //    65,536: C_q^T
    float* LUTDT = (float*)S0;                              // 4 MB overlay (after GEMM3)
    float* LUTDA = (float*)(ws + 46810368);                 // 67,108,864 (optional)
    const bool biglut = ws_size >= 46810368ull + 67108864ull;

    i8* GQ = (i8*)d_out;                                    // gate_q [2][4096][2048]
    i8* UQ = (i8*)d_out + 16777216;                         // u_q    [2][4096][2048]
    i8* UQT = WQ;                                           // u_qT [2][2048][4096]
    i8* OWQ = XQ;                                           // out_proj q8
    i8* DT8 = HSQ;                                          // dt8 [2][4096][2048]
    i8* YQ  = WQ;                                           // y_q [2][2048][4096]

    hipMemsetAsync(scales, 0, 256, stream);
    hipMemsetAsync(SSMP, 0, 2621440, stream);               // split-K accumulator
    hipMemsetAsync(XWQp, 0, 1048576, stream);               // zero pad rows 160..255

    k_maxabs_all<<<4160, 256, 0, stream>>>(in_proj, conv_w, x_proj, dt_proj, out_proj, scales);

    k_quant_all<<<25744, 256, 0, stream>>>(in_proj, conv_w, x_proj, dt_proj, hidden,
                                           scales, WQ, CWQ, XWQp, DWQ, XQ);

    // GEMM1 (MFMA): proj -> hs_q(HSQ) / gate_q(GQ), int8 [b,d,s]
    k_mgemm<0><<<dim3(64, 32), 256, 0, stream>>>(XQ, WQ, 4096, 8192, 2048, scales + 0, HSQ, GQ);

    k_quant_w<<<8192, 256, 0, stream>>>(out_proj, 8388608LL, scales + 4, OWQ);

    dim3 gc(32, 64, 2);
    k_conv<<<gc, 256, 0, stream>>>(HSQ, CWQ, conv_b, scales + 1, UQ, UQT);

    // GEMM2 (MFMA, split-K=8, int32 atomic partials into SSMP)
    k_mgemm<1><<<dim3(2, 32, 8), 256, 0, stream>>>(UQT, XWQp, 4096, 256, 4096, scales + 2, SSMP, nullptr);

    k_rms<<<4096, 64, 0, stream>>>(SSMP, scales + 2, dt_ln, B_ln, C_ln, DTQb, BQT, CQT);

    // GEMM3 (MFMA): dt8 -> [b,d,s] into HSQ
    k_mgemm<2><<<dim3(32, 32), 256, 0, stream>>>(DTQb, DWQ, 4096, 4096, 128, scales + 3, DT8, nullptr);

    // LUT builders (SSMP/XWQp/DTQb dead now)
    k_lut_all<<<4097, 256, 0, stream>>>(dt_bias, LUTDT, LUTSI);
    if (biglut) {
        k_lut_dA<<<4096, 256, 0, stream>>>(A_log, dt_bias, LUTDA);
        k_scan5<1><<<512, 256, 0, stream>>>(DT8, UQ, GQ, BQT, CQT, LUTDT, LUTSI, LUTDA,
                                            A_log, D_skip, YQ);
    } else {
        k_scan5<0><<<512, 256, 0, stream>>>(DT8, UQ, GQ, BQT, CQT, LUTDT, LUTSI, LUTDT /*unused*/,
                                            A_log, D_skip, YQ);
    }

    // GEMM4 (MFMA): out = y_q @ out_proj^T -> f32
    k_mgemm<3><<<dim3(16, 32), 256, 0, stream>>>(YQ, OWQ, 4096, 2048, 4096, scales + 4, out, nullptr);
}

// Round 14
// 656.100 us; speedup vs baseline: 1.0870x; 1.0870x over previous
//
#include <hip/hip_runtime.h>
#include <stdint.h>

typedef signed char i8;
typedef int v4i __attribute__((ext_vector_type(4)));

#define S_IN  0.05f
#define S_Z   0.02f
#define S_U   0.01f
#define S_DTLN 0.02f
#define S_B   0.02f
#define S_C   0.02f
#define S_DT  0.01f
#define S_Y   0.01f

// qa(): round-half-even (matches jnp.round), clip to [-128,127]
__device__ __forceinline__ float q8f(float x, float s) {
    float r = rintf(x / s);
    return fmaxf(-128.0f, fminf(127.0f, r));
}
__device__ __forceinline__ int q8i(float x, float s) { return (int)q8f(x, s); }

__device__ __forceinline__ float softplus_f(float x) {
    return __fadd_rn(fmaxf(x, 0.0f), log1pf(expf(-fabsf(x))));
}

__device__ __forceinline__ int sbyte_of(int w, int j) {
    return (int)(signed char)((unsigned)w >> (j * 8));
}
__device__ __forceinline__ int ubyte_of(int w, int j) {
    return (int)(((unsigned)w >> (j * 8)) & 255u);
}

// async global->LDS, 16B per lane; LDS dest = wave-uniform base + lane*16
__device__ __forceinline__ void gload16(const i8* g, i8* lds) {
    __builtin_amdgcn_global_load_lds(
        (const __attribute__((address_space(1))) unsigned int*)g,
        (__attribute__((address_space(3))) unsigned int*)lds,
        16, 0, 0);
}

// ---------------- fused max|w| over the 5 weight tensors ----------------
__global__ __launch_bounds__(256)
void k_maxabs_all(const float* __restrict__ a0, const float* __restrict__ a1,
                  const float* __restrict__ a2, const float* __restrict__ a3,
                  const float* __restrict__ a4, unsigned* __restrict__ out) {
    int bid = blockIdx.x;
    const float* w; long long n; int slot, nb;
    if (bid < 2048)      { w = a0; n = 16777216LL; slot = 0; nb = 2048; }
    else if (bid < 2112) { w = a1; n = 16384LL;    slot = 1; nb = 64;   bid -= 2048; }
    else if (bid < 2624) { w = a2; n = 655360LL;   slot = 2; nb = 512;  bid -= 2112; }
    else if (bid < 3136) { w = a3; n = 524288LL;   slot = 3; nb = 512;  bid -= 2624; }
    else                 { w = a4; n = 8388608LL;  slot = 4; nb = 1024; bid -= 3136; }
    unsigned m = 0;
    long long stride = (long long)nb * 256;
    for (long long i = (long long)bid * 256 + threadIdx.x; i < n; i += stride)
        m = max(m, __float_as_uint(fabsf(w[i])));
    #pragma unroll
    for (int off = 32; off; off >>= 1) {
        unsigned o = (unsigned)__shfl_xor((int)m, off);
        m = max(m, o);
    }
    __shared__ unsigned sm[4];
    if ((threadIdx.x & 63) == 0) sm[threadIdx.x >> 6] = m;
    __syncthreads();
    if (threadIdx.x == 0) {
        unsigned r = max(max(sm[0], sm[1]), max(sm[2], sm[3]));
        atomicMax(out + slot, r);
    }
}

// ---------------- fused quant: 5 weights + hidden activation ----------------
// blocks: [0,16384) in_proj | [16384,16400) conv | [16400,17040) x_proj |
//         [17040,17552) dt_proj | [17552,25744) out_proj | [25744,33936) hidden
__global__ __launch_bounds__(256)
void k_quant_all(const float* __restrict__ a0, const float* __restrict__ a1,
                 const float* __restrict__ a2, const float* __restrict__ a3,
                 const float* __restrict__ a4, const float* __restrict__ ax,
                 const unsigned* __restrict__ scales,
                 i8* __restrict__ o0, i8* __restrict__ o1, i8* __restrict__ o2,
                 i8* __restrict__ o3, i8* __restrict__ o4, i8* __restrict__ ox) {
    int bid = blockIdx.x;
    const float* w; i8* o; float s;
    if (bid < 16384)      { w = a0; o = o0; s = __uint_as_float(scales[0]) / 127.0f; }
    else if (bid < 16400) { w = a1; o = o1; s = __uint_as_float(scales[1]) / 127.0f; bid -= 16384; }
    else if (bid < 17040) { w = a2; o = o2; s = __uint_as_float(scales[2]) / 127.0f; bid -= 16400; }
    else if (bid < 17552) { w = a3; o = o3; s = __uint_as_float(scales[3]) / 127.0f; bid -= 17040; }
    else if (bid < 25744) { w = a4; o = o4; s = __uint_as_float(scales[4]) / 127.0f; bid -= 17552; }
    else                  { w = ax; o = ox; s = S_IN;                                 bid -= 25744; }
    long long i = ((long long)bid * 256 + threadIdx.x) * 4;
    float4 v = *(const float4*)(w + i);
    unsigned pk = ((unsigned)(q8i(v.x, s) & 255))
                | ((unsigned)(q8i(v.y, s) & 255) << 8)
                | ((unsigned)(q8i(v.z, s) & 255) << 16)
                | ((unsigned)(q8i(v.w, s) & 255) << 24);
    *(unsigned*)(o + i) = pk;
}

// ---------------- MFMA int8 GEMM: LDS-staged, 128x128 tile, BK=128 bytes ----------------
template<int EPI>
__global__ __launch_bounds__(256)
void k_mgemm(const i8* __restrict__ A, const i8* __restrict__ Bw,
             int M, int N, int K,
             const unsigned* __restrict__ wmaxbits,
             void* __restrict__ out0, void* __restrict__ out1) {
    __shared__ i8 sA[16384];
    __shared__ i8 sB[16384];
    const int tid = threadIdx.x;
    const int w = tid >> 6;
    const int l = tid & 63;
    int id = blockIdx.y * gridDim.x + blockIdx.x;
    const int qq = (gridDim.x * gridDim.y) >> 3;
    id = (id & 7) * qq + (id >> 3);
    const int m0 = (id / gridDim.x) << 7;
    const int n0 = (id % gridDim.x) << 7;
    const int kLen = K / gridDim.z;
    const int kOff = blockIdx.z * kLen;
    const int lr = l & 15;
    const int lk = l >> 4;
    const i8* gA = A  + (size_t)(m0 + lr) * K + lk * 16;
    const i8* gB = Bw + (size_t)(n0 + lr) * K + lk * 16;
    const size_t rowK16 = (size_t)16 * K;
    const int mw = (w >> 1) * 4;
    const int nw = (w & 1) * 4;
    const int rdoff = lk * 256 + lr * 16;
    v4i acc[4][4] = {};
    for (int k0 = kOff; k0 < kOff + kLen; k0 += 128) {
        gload16(gA + rowK16 * w + k0,            sA + w * 2048);
        gload16(gA + rowK16 * w + k0 + 64,       sA + w * 2048 + 1024);
        gload16(gA + rowK16 * (4 + w) + k0,      sA + (4 + w) * 2048);
        gload16(gA + rowK16 * (4 + w) + k0 + 64, sA + (4 + w) * 2048 + 1024);
        gload16(gB + rowK16 * w + k0,            sB + w * 2048);
        gload16(gB + rowK16 * w + k0 + 64,       sB + w * 2048 + 1024);
        gload16(gB + rowK16 * (4 + w) + k0,      sB + (4 + w) * 2048);
        gload16(gB + rowK16 * (4 + w) + k0 + 64, sB + (4 + w) * 2048 + 1024);
        __syncthreads();
        #pragma unroll
        for (int k64 = 0; k64 < 2; k64++) {
            v4i af[4], bf[4];
            #pragma unroll
            for (int t = 0; t < 4; t++) {
                af[t] = *(const v4i*)(sA + (mw + t) * 2048 + k64 * 1024 + rdoff);
                bf[t] = *(const v4i*)(sB + (nw + t) * 2048 + k64 * 1024 + rdoff);
            }
            #pragma unroll
            for (int mt = 0; mt < 4; mt++)
                #pragma unroll
                for (int nt = 0; nt < 4; nt++)
                    acc[mt][nt] = __builtin_amdgcn_mfma_i32_16x16x64_i8(af[mt], bf[nt], acc[mt][nt], 0, 0, 0);
        }
        __syncthreads();
    }
    const float wsc = __uint_as_float(*wmaxbits) / 127.0f;
    const int m0w = m0 + (w >> 1) * 64;
    const int n0w = n0 + (w & 1) * 64;
    if constexpr (EPI == 0 || EPI == 2) {
        const float sc = (EPI == 0 ? S_IN : S_DTLN) * wsc;
        const float qs = (EPI == 0 ? S_Z : S_DT);
        const int b = m0w >> 11;
        #pragma unroll
        for (int nt = 0; nt < 4; nt++) {
            const int j = n0w + nt * 16 + lr;
            i8* dst;
            if constexpr (EPI == 0) dst = (j < 4096) ? (i8*)out0 : (i8*)out1;
            else dst = (i8*)out0;
            const int jj = j & 4095;
            #pragma unroll
            for (int mt = 0; mt < 4; mt++) {
                const int sbase = (m0w & 2047) + mt * 16 + lk * 4;
                unsigned pk = 0;
                #pragma unroll
                for (int r = 0; r < 4; r++) {
                    float v = (float)acc[mt][nt][r] * sc;
                    pk |= ((unsigned)(q8i(v, qs) & 255)) << (8 * r);
                }
                *(unsigned*)(dst + ((size_t)b * 4096 + jj) * 2048 + sbase) = pk;
            }
        }
    } else if constexpr (EPI == 1) {
        int* O = (int*)out0;
        #pragma unroll
        for (int mt = 0; mt < 4; mt++)
            #pragma unroll
            for (int r = 0; r < 4; r++) {
                const int m = m0w + mt * 16 + lk * 4 + r;
                #pragma unroll
                for (int nt = 0; nt < 4; nt++) {
                    const int j = n0w + nt * 16 + lr;
                    if (j < 160)
                        atomicAdd(O + (size_t)m * 160 + j, acc[mt][nt][r]);
                }
            }
    } else {
        const float sc = S_Y * wsc;
        float* O = (float*)out0;
        #pragma unroll
        for (int mt = 0; mt < 4; mt++)
            #pragma unroll
            for (int r = 0; r < 4; r++) {
                const int m = m0w + mt * 16 + lk * 4 + r;
                #pragma unroll
                for (int nt = 0; nt < 4; nt++)
                    O[(size_t)m * N + n0w + nt * 16 + lr] = (float)acc[mt][nt][r] * sc;
            }
    }
}

// ---------------- depthwise causal conv(K=4) + silu + quant ----------------
__global__ __launch_bounds__(256)
void k_conv(const i8* __restrict__ hsq, const i8* __restrict__ cwq,
            const float* __restrict__ conv_b, const unsigned* __restrict__ cmaxbits,
            i8* __restrict__ uq, i8* __restrict__ uqT) {
    __shared__ char lt[64][68];
    const int tid = threadIdx.x;
    const int b = blockIdx.z;
    const int d0 = blockIdx.y << 6;
    const int s0 = blockIdx.x << 6;
    const int dl = tid >> 2;
    const int sg = tid & 3;
    const int d = d0 + dl;
    const int sbase = s0 + (sg << 4);
    const i8* xp = hsq + ((size_t)b * 4096 + d) * 2048;
    int v[19];
    #pragma unroll
    for (int i = 0; i < 19; i++) {
        int s = sbase - 3 + i;
        v[i] = (s >= 0) ? (int)xp[s] : 0;
    }
    const unsigned cw = *(const unsigned*)(cwq + (size_t)d * 4);
    const int w0 = (int)(char)(cw & 255);
    const int w1 = (int)(char)((cw >> 8) & 255);
    const int w2 = (int)(char)((cw >> 16) & 255);
    const int w3 = (int)(char)((cw >> 24) & 255);
    const float cws = __uint_as_float(*cmaxbits) / 127.0f;
    const float sc = S_Z * cws;
    const float bias = conv_b[d];
    unsigned pk[4] = {0, 0, 0, 0};
    #pragma unroll
    for (int t = 0; t < 16; t++) {
        int acc = v[t] * w0 + v[t + 1] * w1 + v[t + 2] * w2 + v[t + 3] * w3;
        float f = __fadd_rn(__fmul_rn((float)acc, sc), bias);
        float sig = 1.0f / (1.0f + expf(-f));
        float sl = __fmul_rn(f, sig);
        int q = q8i(sl, S_U);
        pk[t >> 2] |= ((unsigned)(q & 255)) << ((t & 3) * 8);
        lt[(sg << 4) + t][dl] = (char)q;
    }
    *(int4*)(uq + ((size_t)b * 4096 + d) * 2048 + sbase) = make_int4(pk[0], pk[1], pk[2], pk[3]);
    __syncthreads();
    const int rr = tid >> 2;
    const int wg = tid & 3;
    const int* rp = (const int*)(&lt[rr][wg << 4]);
    int4 o; o.x = rp[0]; o.y = rp[1]; o.z = rp[2]; o.w = rp[3];
    *(int4*)(uqT + ((size_t)b * 2048 + s0 + rr) * 4096 + d0 + (wg << 4)) = o;
}

// ---------------- rmsnorm + quant; input int32 partials; B/C transposed ----------------
__global__ __launch_bounds__(64)
void k_rms(const int* __restrict__ p, const unsigned* __restrict__ xsc,
           const float* __restrict__ wdt, const float* __restrict__ wB, const float* __restrict__ wC,
           i8* __restrict__ dtq, i8* __restrict__ bqT, i8* __restrict__ cqT) {
    const int row = blockIdx.x;
    const int lane = threadIdx.x;
    const float scp = S_U * (__uint_as_float(*xsc) / 127.0f);
    const int* x = p + (size_t)row * 160;
    float a0 = (float)x[lane] * scp;
    float a1 = (float)x[64 + lane] * scp;
    float bb = (lane < 16) ? (float)x[128 + lane] * scp : 0.0f;
    float cc = (lane < 16) ? (float)x[144 + lane] * scp : 0.0f;
    float sdt = __fadd_rn(__fmul_rn(a0, a0), __fmul_rn(a1, a1));
    float sB = __fmul_rn(bb, bb);
    float sC = __fmul_rn(cc, cc);
    #pragma unroll
    for (int off = 32; off; off >>= 1) {
        sdt = __fadd_rn(sdt, __shfl_xor(sdt, off));
        sB  = __fadd_rn(sB,  __shfl_xor(sB, off));
        sC  = __fadd_rn(sC,  __shfl_xor(sC, off));
    }
    float rdt = 1.0f / sqrtf(sdt / 128.0f + 1e-6f);
    float rB  = 1.0f / sqrtf(sB / 16.0f + 1e-6f);
    float rC  = 1.0f / sqrtf(sC / 16.0f + 1e-6f);
    dtq[(size_t)row * 128 + lane]      = (i8)q8i(__fmul_rn(wdt[lane],      __fmul_rn(a0, rdt)), S_DTLN);
    dtq[(size_t)row * 128 + 64 + lane] = (i8)q8i(__fmul_rn(wdt[64 + lane], __fmul_rn(a1, rdt)), S_DTLN);
    if (lane < 16) {
        size_t tpos = ((size_t)(row >> 11) * 16 + lane) * 2048 + (row & 2047);
        bqT[tpos] = (i8)q8i(__fmul_rn(wB[lane], __fmul_rn(bb, rB)), S_B);
        cqT[tpos] = (i8)q8i(__fmul_rn(wC[lane], __fmul_rn(cc, rC)), S_C);
    }
}

// ---------------- fused LUT builder: blocks 0..4095 dt rows, block 4096 silu ----------------
__global__ __launch_bounds__(256)
void k_lut_all(const float* __restrict__ dt_bias, float* __restrict__ lutdt,
               float* __restrict__ lutsi) {
    const int q = threadIdx.x;
    const int sv = (q < 128) ? q : q - 256;
    if (blockIdx.x < 4096) {
        const int d = blockIdx.x;
        const float bias = dt_bias[d];
        lutdt[(size_t)d * 256 + q] =
            softplus_f(__fadd_rn(__fmul_rn((float)sv, S_DT), bias));
    } else {
        float gv = __fmul_rn((float)sv, S_Z);
        float sg = __fmul_rn(gv, 1.0f / (1.0f + expf(-gv)));
        lutsi[q] = sg;
    }
}

// ---------------- scan v4 (r11 config): 16-step tiles + reduce-scatter tree ----------------
__global__ __launch_bounds__(256)
void k_scan4(const i8* __restrict__ dt8, const i8* __restrict__ uq, const i8* __restrict__ gq,
             const i8* __restrict__ BqT, const i8* __restrict__ CqT,
             const float* __restrict__ lut_dt, const float* __restrict__ lut_silu,
             const float* __restrict__ A_log, const float* __restrict__ D_skip,
             i8* __restrict__ yq) {
    const int g = blockIdx.x * 256 + threadIdx.x;
    const int n = g & 15;
    const int bd = g >> 4;
    const int d = bd & 4095;
    const int b = bd >> 12;
    const float Acoef = -expf(A_log[(size_t)d * 16 + n]);
    const float Dd = D_skip[d];
    const float* ldt = lut_dt + (size_t)d * 256;
    const v4i* dtp = (const v4i*)(dt8 + (size_t)bd * 2048);
    const v4i* up  = (const v4i*)(uq  + (size_t)bd * 2048);
    const v4i* gp  = (const v4i*)(gq  + (size_t)bd * 2048);
    const v4i* Bp  = (const v4i*)(BqT + ((size_t)b * 16 + n) * 2048);
    const v4i* Cp  = (const v4i*)(CqT + ((size_t)b * 16 + n) * 2048);
    i8* yp = yq + (size_t)b * 2048 * 4096 + d;
    float h = 0.0f;
    v4i dtw = dtp[0], uw = up[0], gw = gp[0], bw = Bp[0], cw = Cp[0];
    for (int t = 0; t < 128; t++) {
        v4i ndt, nu, ng, nb, nc;
        if (t < 127) { ndt = dtp[t + 1]; nu = up[t + 1]; ng = gp[t + 1]; nb = Bp[t + 1]; nc = Cp[t + 1]; }
        float dtv[16], dA[16], pj[16], Cv[16], y[16];
        #pragma unroll
        for (int j = 0; j < 16; j++)
            dtv[j] = ldt[ubyte_of(dtw[j >> 2], j & 3)];
        #pragma unroll
        for (int j = 0; j < 16; j++)
            dA[j] = expf(__fmul_rn(dtv[j], Acoef));
        #pragma unroll
        for (int j = 0; j < 16; j++) {
            float uv = __fmul_rn((float)sbyte_of(uw[j >> 2], j & 3), S_U);
            float Bv = __fmul_rn((float)sbyte_of(bw[j >> 2], j & 3), S_B);
            Cv[j] = __fmul_rn((float)sbyte_of(cw[j >> 2], j & 3), S_C);
            pj[j] = __fmul_rn(__fmul_rn(dtv[j], uv), Bv);
        }
        #pragma unroll
        for (int j = 0; j < 16; j++) {
            h = __fadd_rn(__fmul_rn(h, dA[j]), pj[j]);
            y[j] = __fmul_rn(h, Cv[j]);
        }
        // reduce-scatter: same pairwise tree as the xor-1/2/4/8 butterfly (bit-exact)
        float w8[8];
        #pragma unroll
        for (int i = 0; i < 8; i++) {
            float a = y[2 * i], bq = y[2 * i + 1];
            float snd = (n & 1) ? a : bq;
            float rcv = __shfl_xor(snd, 1);
            float kept = (n & 1) ? bq : a;
            w8[i] = __fadd_rn(kept, rcv);
        }
        float w4[4];
        #pragma unroll
        for (int i = 0; i < 4; i++) {
            float a = w8[2 * i], bq = w8[2 * i + 1];
            float snd = (n & 2) ? a : bq;
            float rcv = __shfl_xor(snd, 2);
            float kept = (n & 2) ? bq : a;
            w4[i] = __fadd_rn(kept, rcv);
        }
        float w2[2];
        #pragma unroll
        for (int i = 0; i < 2; i++) {
            float a = w4[2 * i], bq = w4[2 * i + 1];
            float snd = (n & 4) ? a : bq;
            float rcv = __shfl_xor(snd, 4);
            float kept = (n & 4) ? bq : a;
            w2[i] = __fadd_rn(kept, rcv);
        }
        float ysave;
        {
            float a = w2[0], bq = w2[1];
            float snd = (n & 8) ? a : bq;
            float rcv = __shfl_xor(snd, 8);
            float kept = (n & 8) ? bq : a;
            ysave = __fadd_rn(kept, rcv);
        }
        // epilogue: lane n handles s = t*16 + n
        int uws = (n & 8) ? ((n & 4) ? uw[3] : uw[2]) : ((n & 4) ? uw[1] : uw[0]);
        int gws = (n & 8) ? ((n & 4) ? gw[3] : gw[2]) : ((n & 4) ? gw[1] : gw[0]);
        float uvn = __fmul_rn((float)(int)(signed char)((unsigned)uws >> ((n & 3) * 8)), S_U);
        int gb = (int)(((unsigned)gws >> ((n & 3) * 8)) & 255u);
        float ys = __fadd_rn(ysave, __fmul_rn(uvn, Dd));
        float sg = lut_silu[gb];
        float vv = __fmul_rn(ys, sg);
        yp[(size_t)(t * 16 + n) * 4096] = (i8)q8i(vv, S_Y);
        if (t < 127) { dtw = ndt; uw = nu; gw = ng; bw = nb; cw = nc; }
    }
}

extern "C" void kernel_launch(void* const* d_in, const int* in_sizes, int n_in,
                              void* d_out, int out_size, void* d_ws, size_t ws_size,
                              hipStream_t stream) {
    const float* hidden   = (const float*)d_in[0];
    const float* in_proj  = (const float*)d_in[1];
    const float* conv_w   = (const float*)d_in[2];
    const float* conv_b   = (const float*)d_in[3];
    const float* x_proj   = (const float*)d_in[4];
    const float* dt_ln    = (const float*)d_in[5];
    const float* B_ln     = (const float*)d_in[6];
    const float* C_ln     = (const float*)d_in[7];
    const float* dt_proj  = (const float*)d_in[8];
    const float* dt_bias  = (const float*)d_in[9];
    const float* A_log    = (const float*)d_in[10];
    const float* D_skip   = (const float*)d_in[11];
    const float* out_proj = (const float*)d_in[12];
    float* out = (float*)d_out;

    // ---- workspace layout: 55,198,976 B high-water (ws_size >= 114MB proven r12/r13) ----
    char* ws = (char*)d_ws;
    unsigned* scales = (unsigned*)ws;                       // 256 B
    i8* WQ   = (i8*)(ws + 256);                             // 16,777,216: in_proj q8 -> u_qT -> y_q
    i8* XQ   = (i8*)(ws + 16777472);                        //  8,388,608: x_q
    i8* HSQ  = (i8*)(ws + 25166080);                        // 16,777,216: hs_q -> dt8
    char* S0 = ws + 41943296;
    int*  SSMP = (int*)S0;                                  // 2,621,440: ssm_p int32 [4096][160]
    i8* XWQp = (i8*)(S0 + 2621440);                         // 1,048,576: x_proj q8 padded [256][4096]
    i8* DTQb = (i8*)(S0 + 3670016);                         //   524,288: dt_q [4096][128]
    i8* DWQ  = (i8*)(S0 + 4194304);                         //   524,288: dt_proj q8
    i8* CWQ  = (i8*)(S0 + 4718592);                         //    16,384: conv q8
    float* LUTSI = (float*)(S0 + 4734976);                  //     1,024
    i8* BQT  = (i8*)(S0 + 4736000);                         //    65,536: B_q^T [2][16][2048]
    i8* CQT  = (i8*)(S0 + 4801536);                         //    65,536: C_q^T
    float* LUTDT = (float*)S0;                              // 4 MB overlay (built after GEMM3)
    i8* OWQ  = (i8*)(ws + 46810368);                        // 8,388,608: out_proj q8 (own region)

    i8* GQ = (i8*)d_out;                                    // gate_q [2][4096][2048]
    i8* UQ = (i8*)d_out + 16777216;                         // u_q    [2][4096][2048]
    i8* UQT = WQ;                                           // u_qT [2][2048][4096]
    i8* DT8 = HSQ;                                          // dt8 [2][4096][2048]
    i8* YQ  = WQ;                                           // y_q [2][2048][4096]

    hipMemsetAsync(scales, 0, 256, stream);
    hipMemsetAsync(SSMP, 0, 2621440, stream);               // split-K accumulator
    hipMemsetAsync(XWQp, 0, 1048576, stream);               // zero pad rows 160..255

    k_maxabs_all<<<4160, 256, 0, stream>>>(in_proj, conv_w, x_proj, dt_proj, out_proj, scales);

    // fused quant: all 5 weights + hidden
    k_quant_all<<<33936, 256, 0, stream>>>(in_proj, conv_w, x_proj, dt_proj, out_proj, hidden,
                                           scales, WQ, CWQ, XWQp, DWQ, OWQ, XQ);

    // GEMM1 (MFMA): proj -> hs_q(HSQ) / gate_q(GQ), int8 [b,d,s]
    k_mgemm<0><<<dim3(64, 32), 256, 0, stream>>>(XQ, WQ, 4096, 8192, 2048, scales + 0, HSQ, GQ);

    dim3 gc(32, 64, 2);
    k_conv<<<gc, 256, 0, stream>>>(HSQ, CWQ, conv_b, scales + 1, UQ, UQT);

    // GEMM2 (MFMA, split-K=8, int32 atomic partials into SSMP)
    k_mgemm<1><<<dim3(2, 32, 8), 256, 0, stream>>>(UQT, XWQp, 4096, 256, 4096, scales + 2, SSMP, nullptr);

    k_rms<<<4096, 64, 0, stream>>>(SSMP, scales + 2, dt_ln, B_ln, C_ln, DTQb, BQT, CQT);

    // GEMM3 (MFMA): dt8 -> [b,d,s] into HSQ
    k_mgemm<2><<<dim3(32, 32), 256, 0, stream>>>(DTQb, DWQ, 4096, 4096, 128, scales + 3, DT8, nullptr);

    // LUT builders (SSMP/XWQp/DTQb dead now)
    k_lut_all<<<4097, 256, 0, stream>>>(dt_bias, LUTDT, LUTSI);

    k_scan4<<<512, 256, 0, stream>>>(DT8, UQ, GQ, BQT, CQT, LUTDT, LUTSI, A_log, D_skip, YQ);

    // GEMM4 (MFMA): out = y_q @ out_proj^T -> f32
    k_mgemm<3><<<dim3(16, 32), 256, 0, stream>>>(YQ, OWQ, 4096, 2048, 4096, scales + 4, out, nullptr);
}